// Round 1
// baseline (821.343 us; speedup 1.0000x reference)
//
#include <hip/hip_runtime.h>

typedef __attribute__((ext_vector_type(8))) short short8;
typedef __attribute__((ext_vector_type(4))) float f32x4;

#define AS1 __attribute__((address_space(1)))
#define AS3 __attribute__((address_space(3)))

// sizes
#define NB 16384      // batch
#define LDIM 256
#define CDIM 512
#define HDIM 1024

__device__ __forceinline__ unsigned short f2bf(float x) {
    unsigned u = __float_as_uint(x);
    u += 0x7fffu + ((u >> 16) & 1u);   // RNE; inputs are finite, no NaN guard needed
    return (unsigned short)(u >> 16);
}

__device__ __forceinline__ void gld_lds16(const unsigned short* g, unsigned short* l) {
    __builtin_amdgcn_global_load_lds((const AS1 void*)g, (AS3 void*)l, 16, 0, 0);
}

__device__ __forceinline__ float tanh_fast(float x) {
    x = fminf(fmaxf(x, -15.f), 15.f);
    float e = __expf(2.f * x);
    return (e - 1.f) / (e + 1.f);
}

// ---------------- weight conversion / transpose ----------------
// W1T (2048 x 1024 bf16): rows 0..1023 = Wc1^T, rows 1024..2047 = Wh1^T (k<512), 0 else
// W2T (512 x 1024 bf16):  rows 0..255  = Wc2^T, rows 256..511  = Wh2^T
// bias1 (2048 f32) = [bc1|bh1]; bias2 (512 f32) = [bc2|bh2]
__global__ void build_w(const float* __restrict__ Wc1, const float* __restrict__ bc1,
                        const float* __restrict__ Wc2, const float* __restrict__ bc2,
                        const float* __restrict__ Wh1, const float* __restrict__ bh1,
                        const float* __restrict__ Wh2, const float* __restrict__ bh2,
                        unsigned short* __restrict__ W1T, unsigned short* __restrict__ W2T,
                        float* __restrict__ bias1, float* __restrict__ bias2)
{
    const int R1 = 2048 * 1024;
    const int R2 = R1 + 512 * 1024;
    const int R3 = R2 + 2048;
    const int R4 = R3 + 512;
    int id = blockIdx.x * 256 + threadIdx.x;
    if (id < R1) {
        int n = id >> 10, k = id & 1023;
        float v;
        if (n < 1024) v = Wc1[k * 1024 + n];
        else          v = (k < 512) ? Wh1[k * 1024 + (n - 1024)] : 0.f;
        W1T[id] = f2bf(v);
    } else if (id < R2) {
        int id2 = id - R1;
        int n = id2 >> 10, k = id2 & 1023;
        float v = (n < 256) ? Wc2[k * 256 + n] : Wh2[k * 256 + (n - 256)];
        W2T[id2] = f2bf(v);
    } else if (id < R3) {
        int n = id - R2;
        bias1[n] = (n < 1024) ? bc1[n] : bh1[n - 1024];
    } else if (id < R4) {
        int n = id - R3;
        bias2[n] = (n < 256) ? bc2[n] : bh2[n - 256];
    }
}

// ---------------- A1 = bf16([pm | ctx[:, i]])  (16384 x 1024) ----------------
__global__ void build_A1(const float* __restrict__ z, const float* __restrict__ ts,
                         const float* __restrict__ t, const float* __restrict__ ctx,
                         unsigned short* __restrict__ A1)
{
    __shared__ int sh_i;
    if (threadIdx.x == 0) {
        float tv = t[0];
        int c = 0;
        #pragma unroll
        for (int q = 0; q < 16; ++q) c += (ts[q] <= tv) ? 1 : 0;   // searchsorted 'right'
        sh_i = (c < 15) ? c : 15;
    }
    __syncthreads();
    const int i = sh_i;
    size_t id = (size_t)blockIdx.x * 256 + threadIdx.x;  // exactly 16384*1024 threads
    int b = (int)(id >> 10);
    int col = (int)(id & 1023);
    float v = (col < 512) ? z[(size_t)b * 513 + col]
                          : ctx[((size_t)b * 16 + i) * 512 + (col - 512)];
    A1[id] = f2bf(v);
}

// ---------------- bf16 MFMA GEMM, m97 structure ----------------
// 128x128 tile, BK=32, 4 waves of 64x64, 16x16x32 MFMA.
// A  : M x lda row-major bf16
// BT : N x 1024 row-major bf16 (i.e. W^T)
// LAYER==1: C = tanh(A @ W1 + bias1) -> H bf16 (ldc 2048); ntile>=8 uses K=512
// LAYER==2: C = A' @ W2 + bias2 -> PR f32 (ldc 512); ntile>=2 uses A col offset 1024
template<int LAYER>
__global__ __launch_bounds__(256)
void gemm_tile(const unsigned short* __restrict__ A, const unsigned short* __restrict__ BT,
               const float* __restrict__ bias,
               unsigned short* __restrict__ Hout, float* __restrict__ Fout)
{
    __shared__ unsigned short sA[128 * 32];
    __shared__ unsigned short sB[128 * 32];

    const int tid  = threadIdx.x;
    const int lane = tid & 63;
    const int wave = tid >> 6;
    const int ntile = blockIdx.x;
    const int mtile = blockIdx.y;

    int lda, aoff, kdim;
    if (LAYER == 1) { lda = 1024; aoff = 0;                       kdim = (ntile < 8) ? 1024 : 512; }
    else            { lda = 2048; aoff = (ntile < 2) ? 0 : 1024;  kdim = 1024; }

    const int m0 = mtile * 128;
    const int n0 = ntile * 128;

    // staging: 2 rounds x 256 threads x 16B cover one 128x32 bf16 tile (8 KB)
    const int row0 = tid >> 2,         cb0 = tid & 3;
    const int row1 = (256 + tid) >> 2, cb1 = (256 + tid) & 3;

    const unsigned short* aG0 = A + (size_t)(m0 + row0) * lda + aoff + cb0 * 8;
    const unsigned short* aG1 = A + (size_t)(m0 + row1) * lda + aoff + cb1 * 8;
    const unsigned short* bG0 = BT + (size_t)(n0 + row0) * 1024 + cb0 * 8;
    const unsigned short* bG1 = BT + (size_t)(n0 + row1) * 1024 + cb1 * 8;

    // wave-uniform LDS bases (HW adds lane*16B)
    unsigned short* sA0 = sA + (size_t)(wave * 64) * 8;
    unsigned short* sA1 = sA + (size_t)(256 + wave * 64) * 8;
    unsigned short* sB0 = sB + (size_t)(wave * 64) * 8;
    unsigned short* sB1 = sB + (size_t)(256 + wave * 64) * 8;

    const int wm = (wave & 1) * 64;
    const int wn = (wave >> 1) * 64;
    const int lr = lane & 15;
    const int kq = (lane >> 4) * 8;

    f32x4 acc[4][4] = {};

    for (int k0 = 0; k0 < kdim; k0 += 32) {
        gld_lds16(aG0 + k0, sA0);
        gld_lds16(aG1 + k0, sA1);
        gld_lds16(bG0 + k0, sB0);
        gld_lds16(bG1 + k0, sB1);
        __syncthreads();

        short8 af[4], bfr[4];
        #pragma unroll
        for (int i = 0; i < 4; ++i)
            af[i] = *(const short8*)&sA[(wm + i * 16 + lr) * 32 + kq];
        #pragma unroll
        for (int i = 0; i < 4; ++i)
            bfr[i] = *(const short8*)&sB[(wn + i * 16 + lr) * 32 + kq];

        #pragma unroll
        for (int i = 0; i < 4; ++i)
            #pragma unroll
            for (int j = 0; j < 4; ++j)
                acc[i][j] = __builtin_amdgcn_mfma_f32_16x16x32_bf16(af[i], bfr[j], acc[i][j], 0, 0, 0);
        __syncthreads();
    }

    // epilogue: C/D layout col=lane&15, row=(lane>>4)*4+reg
    const int rquad = (lane >> 4) * 4;
    #pragma unroll
    for (int i = 0; i < 4; ++i) {
        const int gr = m0 + wm + i * 16 + rquad;
        #pragma unroll
        for (int j = 0; j < 4; ++j) {
            const int gc = n0 + wn + j * 16 + lr;
            const float bs = bias[gc];
            #pragma unroll
            for (int r = 0; r < 4; ++r) {
                float x = acc[i][j][r] + bs;
                if (LAYER == 1) {
                    Hout[(size_t)(gr + r) * 2048 + gc] = f2bf(tanh_fast(x));
                } else {
                    Fout[(size_t)(gr + r) * 512 + gc] = x;
                }
            }
        }
    }
}

// ---------------- final assembly + dkl reduction ----------------
__global__ void finalize(const float* __restrict__ z,
                         const float* __restrict__ inverse_mass,
                         const float* __restrict__ diffusion,
                         const float* __restrict__ PR,
                         float* __restrict__ out)
{
    const int b = blockIdx.x;
    const int j = threadIdx.x;   // 0..255

    float mom  = z[(size_t)b * 513 + 256 + j];
    float pd   = inverse_mass[j] * mom;
    float post = PR[(size_t)b * 512 + j];
    float pri  = PR[(size_t)b * 512 + 256 + j];
    float d    = diffusion[j];
    float sgn  = (d > 0.f) ? 1.f : ((d < 0.f) ? -1.f : 0.f);
    float sd   = (fabsf(d) > 1e-7f) ? d : sgn * 1e-7f;
    float q    = (pri - post) / sd;
    float sq   = q * q;

    // wave reduce (width 64) then cross-wave via LDS
    #pragma unroll
    for (int off = 32; off > 0; off >>= 1) sq += __shfl_down(sq, off, 64);
    __shared__ float ws4[4];
    if ((j & 63) == 0) ws4[j >> 6] = sq;
    __syncthreads();

    float* drift = out + (size_t)b * 513;
    float* dif   = out + (size_t)NB * 513 + (size_t)b * 513;
    drift[j]       = pd;
    drift[256 + j] = post;
    dif[j]         = 0.f;
    dif[256 + j]   = d;
    if (j == 0) {
        drift[512] = ws4[0] + ws4[1] + ws4[2] + ws4[3];
        dif[512]   = 0.f;
    }
}

extern "C" void kernel_launch(void* const* d_in, const int* in_sizes, int n_in,
                              void* d_out, int out_size, void* d_ws, size_t ws_size,
                              hipStream_t stream) {
    const float* z    = (const float*)d_in[0];
    const float* ts   = (const float*)d_in[1];
    const float* t    = (const float*)d_in[2];
    const float* ctx  = (const float*)d_in[3];
    const float* im   = (const float*)d_in[4];
    const float* dfu  = (const float*)d_in[5];
    const float* Wc1  = (const float*)d_in[6];
    const float* bc1  = (const float*)d_in[7];
    const float* Wc2  = (const float*)d_in[8];
    const float* bc2  = (const float*)d_in[9];
    const float* Wh1  = (const float*)d_in[10];
    const float* bh1  = (const float*)d_in[11];
    const float* Wh2  = (const float*)d_in[12];
    const float* bh2  = (const float*)d_in[13];

    char* ws = (char*)d_ws;
    unsigned short* A1  = (unsigned short*)(ws);                       // 33,554,432 B
    unsigned short* H   = (unsigned short*)(ws + 33554432ull);         // 67,108,864 B
    unsigned short* W1T = (unsigned short*)(ws + 100663296ull);        //  4,194,304 B
    unsigned short* W2T = (unsigned short*)(ws + 104857600ull);        //  1,048,576 B
    float*          b1  = (float*)(ws + 105906176ull);                 //      8,192 B
    float*          b2  = (float*)(ws + 105914368ull);                 //      2,048 B
    float*          PR  = (float*)(ws + 105916416ull);                 // 33,554,432 B  (end ~139.5 MB)

    build_w<<<10250, 256, 0, stream>>>(Wc1, bc1, Wc2, bc2, Wh1, bh1, Wh2, bh2, W1T, W2T, b1, b2);
    build_A1<<<65536, 256, 0, stream>>>(z, ts, t, ctx, A1);

    dim3 g1(16, 128);
    gemm_tile<1><<<g1, 256, 0, stream>>>(A1, W1T, b1, H, nullptr);
    dim3 g2(4, 128);
    gemm_tile<2><<<g2, 256, 0, stream>>>(H, W2T, b2, nullptr, PR);

    finalize<<<NB, 256, 0, stream>>>(z, im, dfu, PR, (float*)d_out);
}